// Round 14
// baseline (203.076 us; speedup 1.0000x reference)
//
#include <hip/hip_runtime.h>

#define DIM 64
#define NCODE 1024

typedef __attribute__((ext_vector_type(8))) short bf16x8;
typedef __attribute__((ext_vector_type(4))) float f32x4;

// ---- small ws (8.3 KB) ----
#define WSO_HIST  0        // float[1024]
#define WSO_LOSS  4096     // float
#define WSO_COUNT 4100     // int
#define WSO_MAX4  4112     // float[4]
#define WSO_CBN   4160     // float[1024]

// ---- big scratch in d_out's out_xq region ----
// cbt (fragment-major bf16 hi/lo) @0       (262144 B) = out_xq rows    0..1023
// cbT (f32 [code][64])            @262144  (262144 B) = out_xq rows 1024..2047
// list (u16 flagged rows)         @524288  (131072 B) = out_xq rows 2048..2559
// Epilogue E1 writes every row EXCEPT 1024..2047 (so cbT stays readable);
// E2 (after E1) writes rows 1024..2047 using the direct-cb gather (no cbT read).

__device__ __forceinline__ unsigned short f2bf(float f) {
    unsigned u = __float_as_uint(f);
    unsigned r = (u + 0x7FFFu + ((u >> 16) & 1u)) >> 16;   // RNE
    return (unsigned short)r;
}

__device__ __forceinline__ void gload16(const void* g, void* l) {
    __builtin_amdgcn_global_load_lds(
        (const __attribute__((address_space(1))) unsigned int*)g,
        (__attribute__((address_space(3))) unsigned int*)l, 16, 0, 0);
}

// ---- kernel 0: prep (4 x 256): cbn, fragment-major bf16 codebook, f32 cbT, zeros ----
__global__ __launch_bounds__(256) void vq_prep(const float* __restrict__ cb,
                                               char* __restrict__ ws,
                                               char* __restrict__ cbt,
                                               float* __restrict__ cbT) {
    __shared__ float red[256];
    const int t = threadIdx.x;
    const int k = blockIdx.x * 256 + t;

    float cv[64];
#pragma unroll
    for (int d = 0; d < DIM; ++d) cv[d] = cb[d * NCODE + k];

    float s = 0.f;
#pragma unroll
    for (int d = 0; d < DIM; ++d) s = fmaf(cv[d], cv[d], s);

    ((float*)(ws + WSO_CBN))[k] = s;
    ((float*)(ws + WSO_HIST))[k] = 0.f;

    unsigned short hi[64], lo[64];
#pragma unroll
    for (int d = 0; d < DIM; ++d) {
        unsigned short h = f2bf(cv[d]);
        float hf = __uint_as_float(((unsigned)h) << 16);
        hi[d] = h;
        lo[d] = f2bf(cv[d] - hf);
    }

    // fragment-major scatter for the MFMA kernel
    const int c = k >> 6, cc = k & 63, wv = cc >> 4, col = cc & 15;
    char* base = cbt + (size_t)(c * 4 + wv) * 4096;
#pragma unroll
    for (int g = 0; g < 4; ++g) {
        bf16x8 h0v, h1v, l0v, l1v;
#pragma unroll
        for (int e = 0; e < 8; ++e) {
            h0v[e] = (short)hi[g * 8 + e];
            h1v[e] = (short)hi[32 + g * 8 + e];
            l0v[e] = (short)lo[g * 8 + e];
            l1v[e] = (short)lo[32 + g * 8 + e];
        }
        const int off = (g * 16 + col) * 16;
        *(bf16x8*)(base + off)        = h0v;
        *(bf16x8*)(base + 1024 + off) = h1v;
        *(bf16x8*)(base + 2048 + off) = l0v;
        *(bf16x8*)(base + 3072 + off) = l1v;
    }

    // f32 row-major codebook for the fast epilogue gather
#pragma unroll
    for (int j = 0; j < 16; ++j) {
        float4 v = {cv[4 * j], cv[4 * j + 1], cv[4 * j + 2], cv[4 * j + 3]};
        *(float4*)(cbT + (size_t)k * 64 + 4 * j) = v;
    }

    red[t] = s;
    __syncthreads();
    for (int m = 128; m > 0; m >>= 1) {
        if (t < m) red[t] = fmaxf(red[t], red[t + m]);
        __syncthreads();
    }
    if (t == 0) {
        ((float*)(ws + WSO_MAX4))[blockIdx.x] = red[0];
        if (blockIdx.x == 0) {
            *(float*)(ws + WSO_LOSS) = 0.f;
            *(int*)(ws + WSO_COUNT) = 0;
        }
    }
}

// ---- kernel 1: double-bf16 MFMA distances, barrier-free hot loop (R13 verbatim) ----
__global__ __launch_bounds__(256, 2) void vq_mfma(const float* __restrict__ x,
                                                  const char* __restrict__ cbt,
                                                  char* __restrict__ ws,
                                                  unsigned short* __restrict__ list,
                                                  float* __restrict__ out_idx) {
    __shared__ __align__(16) char sm[20736];
    char*  bX    = sm;
    float* cbn_s = (float*)(sm + 16384);
    float* xx_s  = (float*)(sm + 20480);
    float* R1    = (float*)sm;
    float* R2v   = R1 + 256;
    int*   RIv   = (int*)(R2v + 256);

    const int t = threadIdx.x, w = t >> 6, lane = t & 63;
    const int r0 = blockIdx.x * 64;

    const float* mb4 = (const float*)(ws + WSO_MAX4);
    const float maxcbn = fmaxf(fmaxf(mb4[0], mb4[1]), fmaxf(mb4[2], mb4[3]));

    gload16((const char*)(ws + WSO_CBN) + ((size_t)w * 64 + lane) * 16, (char*)cbn_s + w * 1024);

    {
        const int row = t >> 2, q = t & 3;
        const float4* xp = (const float4*)(x + (size_t)(r0 + row) * DIM + q * 16);
        float4 v0 = xp[0], v1 = xp[1], v2 = xp[2], v3 = xp[3];
        float p = 0.f;
        p = fmaf(v0.x, v0.x, p); p = fmaf(v0.y, v0.y, p); p = fmaf(v0.z, v0.z, p); p = fmaf(v0.w, v0.w, p);
        p = fmaf(v1.x, v1.x, p); p = fmaf(v1.y, v1.y, p); p = fmaf(v1.z, v1.z, p); p = fmaf(v1.w, v1.w, p);
        p = fmaf(v2.x, v2.x, p); p = fmaf(v2.y, v2.y, p); p = fmaf(v2.z, v2.z, p); p = fmaf(v2.w, v2.w, p);
        p = fmaf(v3.x, v3.x, p); p = fmaf(v3.y, v3.y, p); p = fmaf(v3.z, v3.z, p); p = fmaf(v3.w, v3.w, p);
        p += __shfl_xor(p, 1);
        p += __shfl_xor(p, 2);
        if (q == 0) xx_s[row] = p;

        float hv[16] = {v0.x, v0.y, v0.z, v0.w, v1.x, v1.y, v1.z, v1.w,
                        v2.x, v2.y, v2.z, v2.w, v3.x, v3.y, v3.z, v3.w};
        bf16x8 ph[2], pl[2];
#pragma unroll
        for (int h = 0; h < 2; ++h)
#pragma unroll
            for (int e = 0; e < 8; ++e) {
                float v = hv[h * 8 + e];
                unsigned short hb = f2bf(v);
                float hf = __uint_as_float(((unsigned)hb) << 16);
                ph[h][e] = (short)hb;
                pl[h][e] = (short)f2bf(v - hf);
            }
        const int sw = row & 7;
        char* base = bX + row * 256;
#pragma unroll
        for (int h = 0; h < 2; ++h) {
            int s3 = (2 * q + h) ^ sw;
            *(bf16x8*)(base + (s3 & 7) * 16)        = ph[h];
            *(bf16x8*)(base + (8 | (s3 & 7)) * 16)  = pl[h];
        }
    }
    __syncthreads();

    bf16x8 afh[4][2], afl[4][2];
#pragma unroll
    for (int rt = 0; rt < 4; ++rt)
#pragma unroll
        for (int kt = 0; kt < 2; ++kt) {
            int row = rt * 16 + (lane & 15);
            int s3 = ((kt * 4 + (lane >> 4)) ^ (row & 7)) & 7;
            afh[rt][kt] = *(const bf16x8*)(bX + row * 256 + s3 * 16);
            afl[rt][kt] = *(const bf16x8*)(bX + row * 256 + (8 | s3) * 16);
        }

    const int cl = w * 16 + (lane & 15);

    float m1[16], m2[16];
    int   mi[16];
#pragma unroll
    for (int s = 0; s < 16; ++s) { m1[s] = 3.4e38f; m2[s] = 3.4e38f; mi[s] = 0; }

    const char* pc = cbt + (size_t)w * 4096 + (size_t)lane * 16;

    bf16x8 bh0 = *(const bf16x8*)(pc);
    bf16x8 bh1 = *(const bf16x8*)(pc + 1024);
    bf16x8 bl0 = *(const bf16x8*)(pc + 2048);
    bf16x8 bl1 = *(const bf16x8*)(pc + 3072);

#pragma unroll 1
    for (int c = 0; c < 16; ++c) {
        const char* np = pc + 16384;
        bf16x8 nh0 = *(const bf16x8*)(np);
        bf16x8 nh1 = *(const bf16x8*)(np + 1024);
        bf16x8 nl0 = *(const bf16x8*)(np + 2048);
        bf16x8 nl1 = *(const bf16x8*)(np + 3072);

        const int kg = c * 64 + cl;
        const float cbnv = cbn_s[kg];

#pragma unroll
        for (int rt = 0; rt < 4; ++rt) {
            f32x4 z = {0.f, 0.f, 0.f, 0.f};
            z = __builtin_amdgcn_mfma_f32_16x16x32_bf16(afh[rt][0], bh0, z, 0, 0, 0);
            z = __builtin_amdgcn_mfma_f32_16x16x32_bf16(afh[rt][1], bh1, z, 0, 0, 0);
            z = __builtin_amdgcn_mfma_f32_16x16x32_bf16(afl[rt][0], bh0, z, 0, 0, 0);
            z = __builtin_amdgcn_mfma_f32_16x16x32_bf16(afl[rt][1], bh1, z, 0, 0, 0);
            z = __builtin_amdgcn_mfma_f32_16x16x32_bf16(afh[rt][0], bl0, z, 0, 0, 0);
            z = __builtin_amdgcn_mfma_f32_16x16x32_bf16(afh[rt][1], bl1, z, 0, 0, 0);
#pragma unroll
            for (int v = 0; v < 4; ++v) {
                const int s = rt * 4 + v;
                float dd = fmaf(-2.f, z[v], cbnv);
                bool lt = dd < m1[s];
                m2[s] = fminf(m2[s], fmaxf(m1[s], dd));
                m1[s] = fminf(m1[s], dd);
                mi[s] = lt ? kg : mi[s];
            }
        }
        pc = np;
        bh0 = nh0; bh1 = nh1; bl0 = nl0; bl1 = nl1;
    }

#pragma unroll
    for (int m = 1; m <= 8; m <<= 1) {
#pragma unroll
        for (int s = 0; s < 16; ++s) {
            float o1 = __shfl_xor(m1[s], m);
            float o2 = __shfl_xor(m2[s], m);
            int   oi = __shfl_xor(mi[s], m);
            float nm2 = fminf(fminf(m2[s], o2), fmaxf(m1[s], o1));
            bool tk = (o1 < m1[s]) || (o1 == m1[s] && oi < mi[s]);
            m1[s] = fminf(m1[s], o1);
            mi[s] = tk ? oi : mi[s];
            m2[s] = nm2;
        }
    }
    __syncthreads();
    if ((lane & 15) == 0) {
        const int gq = lane >> 4;
#pragma unroll
        for (int s = 0; s < 16; ++s) {
            const int row = (s >> 2) * 16 + gq * 4 + (s & 3);
            R1[row * 4 + w]  = m1[s];
            R2v[row * 4 + w] = m2[s];
            RIv[row * 4 + w] = mi[s];
        }
    }
    __syncthreads();
    {
        const int row = t >> 2, q = t & 3;
        float a1 = R1[row * 4 + q];
        float A2 = R2v[row * 4 + q];
        int   ai = RIv[row * 4 + q];
#pragma unroll
        for (int m = 1; m <= 2; m <<= 1) {
            float o1 = __shfl_xor(a1, m);
            float o2 = __shfl_xor(A2, m);
            int   oi = __shfl_xor(ai, m);
            float nm2 = fminf(fminf(A2, o2), fmaxf(a1, o1));
            bool tk = (o1 < a1) || (o1 == a1 && oi < ai);
            a1 = fminf(a1, o1);
            ai = tk ? oi : ai;
            A2 = nm2;
        }
        if (q == 0) {
            const int r = r0 + row;
            out_idx[r] = (float)ai;
            const float Bv = 1.5e-4f * sqrtf(xx_s[row] * maxcbn) + 2e-3f;
            if (A2 - a1 <= 2.f * Bv) {
                int pos = atomicAdd((int*)(ws + WSO_COUNT), 1);
                list[pos] = (unsigned short)r;
            }
        }
    }
}

// ---- kernel 2: refine v3 (R12 verbatim) ----
__global__ void vq_refine(const float* __restrict__ x,
                          const float* __restrict__ cb,
                          const char* __restrict__ ws,
                          const unsigned short* __restrict__ list,
                          float* __restrict__ out_idx) {
    const int N = *(const int*)(ws + WSO_COUNT);
    const float* cbn = (const float*)(ws + WSO_CBN);
    __shared__ float rowx[4][64];
    const int t = threadIdx.x, w = t >> 6, lane = t & 63;

    for (int base = blockIdx.x * 4; base < N; base += (int)gridDim.x * 4) {
        const int ii = base + w;
        const bool valid = ii < N;
        const int r = valid ? (int)list[ii] : (int)list[0];

        __syncthreads();
        const float xv = x[(size_t)r * DIM + lane];
        rowx[w][lane] = xv;
        float p = xv * xv;
#pragma unroll
        for (int m = 1; m < 64; m <<= 1) p += __shfl_xor(p, m);
        const float xx = p;
        __syncthreads();

        float xr[64];
#pragma unroll
        for (int d = 0; d < 64; ++d) xr[d] = rowx[w][d];

        float bd = 3.4e38f;
        int   bk = 0;
        for (int kb = 0; kb < NCODE; kb += 64) {
            float d0 = 0.f, d1 = 0.f, d2 = 0.f, d3 = 0.f;
            const float* cp = cb + kb + lane;
#pragma unroll
            for (int d = 0; d < 64; d += 4) {
                d0 = fmaf(xr[d + 0], cp[(d + 0) * NCODE], d0);
                d1 = fmaf(xr[d + 1], cp[(d + 1) * NCODE], d1);
                d2 = fmaf(xr[d + 2], cp[(d + 2) * NCODE], d2);
                d3 = fmaf(xr[d + 3], cp[(d + 3) * NCODE], d3);
            }
            const float dot = (d0 + d1) + (d2 + d3);
            const float dist = fmaf(-2.f, dot, xx) + cbn[kb + lane];
            const int k = kb + lane;
            if (dist < bd) { bd = dist; bk = k; }
        }
#pragma unroll
        for (int m = 1; m < 64; m <<= 1) {
            float od = __shfl_xor(bd, m);
            int   ok = __shfl_xor(bk, m);
            if (od < bd || (od == bd && ok < bk)) { bd = od; bk = ok; }
        }
        if (lane == 0 && valid) out_idx[r] = (float)bk;
    }
}

// ---- kernel 3a: epilogue E1 — fast contiguous gather from cbT; skips rows 1024..2047 ----
// 2016 blocks x 32 rows. Thread = (row = t>>3, q8 = t&7): 8 floats each.
__global__ __launch_bounds__(256) void vq_epi_main(const float* __restrict__ x,
                                                   const float* __restrict__ cbT,
                                                   const float* __restrict__ idx_f,
                                                   float* __restrict__ out_xq,
                                                   char* __restrict__ ws) {
    const int t = threadIdx.x;
    const int r_lin = blockIdx.x * 32 + (t >> 3);        // 0..64511
    const int r = (r_lin < 1024) ? r_lin : r_lin + 1024; // skip cbT rows
    const int q8 = t & 7;
    const int k = (int)idx_f[r];

    const float4* cp = (const float4*)(cbT + (size_t)k * 64 + q8 * 8);
    const float4* xp = (const float4*)(x + (size_t)r * DIM + q8 * 8);
    float4* op = (float4*)(out_xq + (size_t)r * DIM + q8 * 8);

    float4 c0 = cp[0], c1 = cp[1];
    float4 x0 = xp[0], x1 = xp[1];
    float e0 = c0.x - x0.x, e1 = c0.y - x0.y, e2 = c0.z - x0.z, e3 = c0.w - x0.w;
    float e4 = c1.x - x1.x, e5 = c1.y - x1.y, e6 = c1.z - x1.z, e7 = c1.w - x1.w;
    float4 o0, o1;
    o0.x = x0.x + e0; o0.y = x0.y + e1; o0.z = x0.z + e2; o0.w = x0.w + e3;
    o1.x = x1.x + e4; o1.y = x1.y + e5; o1.z = x1.z + e6; o1.w = x1.w + e7;
    op[0] = o0; op[1] = o1;

    float lsum = 0.f;
    lsum = fmaf(e0, e0, lsum); lsum = fmaf(e1, e1, lsum);
    lsum = fmaf(e2, e2, lsum); lsum = fmaf(e3, e3, lsum);
    lsum = fmaf(e4, e4, lsum); lsum = fmaf(e5, e5, lsum);
    lsum = fmaf(e6, e6, lsum); lsum = fmaf(e7, e7, lsum);

    if (q8 == 0) atomicAdd((float*)(ws + WSO_HIST) + k, 1.0f);
#pragma unroll
    for (int off = 1; off < 64; off <<= 1) lsum += __shfl_xor(lsum, off);
    if ((t & 63) == 0) atomicAdd((float*)(ws + WSO_LOSS), lsum);
}

// ---- kernel 3b: epilogue E2 — rows 1024..2047 (the cbT region), direct-cb gather ----
__global__ __launch_bounds__(256) void vq_epi_tail(const float* __restrict__ x,
                                                   const float* __restrict__ cb,
                                                   const float* __restrict__ idx_f,
                                                   float* __restrict__ out_xq,
                                                   char* __restrict__ ws) {
    const int t = threadIdx.x;
    const int row = 1024 + blockIdx.x * 64 + (t >> 2), q = t & 3;
    const int k = (int)idx_f[row];
    const float4* xp = (const float4*)(x + (size_t)row * DIM + q * 16);
    float4* op = (float4*)(out_xq + (size_t)row * DIM + q * 16);
    float lsum = 0.f;
#pragma unroll
    for (int j = 0; j < 4; ++j) {
        float4 xv = xp[j];
        const int d0 = q * 16 + 4 * j;
        float q0 = cb[(d0 + 0) * NCODE + k];
        float q1 = cb[(d0 + 1) * NCODE + k];
        float q2 = cb[(d0 + 2) * NCODE + k];
        float q3 = cb[(d0 + 3) * NCODE + k];
        float e0 = q0 - xv.x, e1 = q1 - xv.y, e2 = q2 - xv.z, e3 = q3 - xv.w;
        float4 o;
        o.x = xv.x + e0; o.y = xv.y + e1; o.z = xv.z + e2; o.w = xv.w + e3;
        op[j] = o;
        lsum = fmaf(e0, e0, lsum); lsum = fmaf(e1, e1, lsum);
        lsum = fmaf(e2, e2, lsum); lsum = fmaf(e3, e3, lsum);
    }
    if (q == 0) atomicAdd((float*)(ws + WSO_HIST) + k, 1.0f);
#pragma unroll
    for (int off = 1; off < 64; off <<= 1) lsum += __shfl_xor(lsum, off);
    if ((t & 63) == 0) atomicAdd((float*)(ws + WSO_LOSS), lsum);
}

// ---- kernel 4: EMA + loss finalize ----
__global__ __launch_bounds__(256) void vq_final(const float* __restrict__ cf,
                                                const char* __restrict__ ws,
                                                float* __restrict__ out_loss,
                                                float* __restrict__ out_freq) {
    int k = blockIdx.x * 256 + threadIdx.x;
    out_freq[k] = 0.95f * cf[k] + 0.05f * ((const float*)(ws + WSO_HIST))[k];
    if (k == 0) {
        float m = *(const float*)(ws + WSO_LOSS) / 4194304.0f;
        out_loss[0] = m + m;
    }
}

extern "C" void kernel_launch(void* const* d_in, const int* in_sizes, int n_in,
                              void* d_out, int out_size, void* d_ws, size_t ws_size,
                              hipStream_t stream) {
    const float* x  = (const float*)d_in[0];   // [16,4096,64]
    const float* cb = (const float*)d_in[1];   // [64,1024]
    const float* cf = (const float*)d_in[2];   // [1024]

    float* out      = (float*)d_out;
    float* out_xq   = out;                     // 4,194,304 floats
    float* out_idx  = out + 4194304;           // 65,536
    float* out_loss = out + 4194304 + 65536;   // 1
    float* out_freq = out_loss + 1;            // 1024

    char* ws = (char*)d_ws;                    // 8,256 bytes used

    // scratch inside out_xq (cbt/cbT/list; E1/E2 split keeps cbT race-free)
    char*           cbt  = (char*)d_out;                               // 262,144 B
    float*          cbT  = (float*)((char*)d_out + 262144);            // 262,144 B
    unsigned short* list = (unsigned short*)((char*)d_out + 524288);   // 131,072 B

    vq_prep    <<<4,    256, 0, stream>>>(cb, ws, cbt, cbT);
    vq_mfma    <<<1024, 256, 0, stream>>>(x, cbt, ws, list, out_idx);
    vq_refine  <<<2048, 256, 0, stream>>>(x, cb, ws, list, out_idx);
    vq_epi_main<<<2016, 256, 0, stream>>>(x, cbT, out_idx, out_xq, ws);
    vq_epi_tail<<<16,   256, 0, stream>>>(x, cb, out_idx, out_xq, ws);
    vq_final   <<<4,    256, 0, stream>>>(cf, ws, out_loss, out_freq);
}

// Round 15
// 153.286 us; speedup vs baseline: 1.3248x; 1.3248x over previous
//
#include <hip/hip_runtime.h>

#define DIM 64
#define NCODE 1024

typedef __attribute__((ext_vector_type(8))) short bf16x8;
typedef __attribute__((ext_vector_type(4))) float f32x4;

// ---- small ws (8.3 KB) ----
#define WSO_HIST  0        // float[1024]
#define WSO_LOSS  4096     // float (unused now)
#define WSO_COUNT 4100     // int
#define WSO_MAX4  4112     // float[4]
#define WSO_CBN   4160     // float[1024]

// ---- big scratch in d_out's out_xq region ----
// cbt (fragment-major bf16 hi/lo) @0       (262144 B) = out_xq rows    0..1023
// cbT (f32 [code][64])            @262144  (262144 B) = out_xq rows 1024..2047
// list (u16 flagged rows)         @524288  (131072 B) = out_xq rows 2048..2559
// loss slots: the out_freq region (1024 floats, only [0..255] used as slots) —
// zeroed by prep, atomically accumulated by E1/E2, consumed+overwritten by final.

__device__ __forceinline__ unsigned short f2bf(float f) {
    unsigned u = __float_as_uint(f);
    unsigned r = (u + 0x7FFFu + ((u >> 16) & 1u)) >> 16;   // RNE
    return (unsigned short)r;
}

__device__ __forceinline__ void gload16(const void* g, void* l) {
    __builtin_amdgcn_global_load_lds(
        (const __attribute__((address_space(1))) unsigned int*)g,
        (__attribute__((address_space(3))) unsigned int*)l, 16, 0, 0);
}

// ---- kernel 0: prep (4 x 256): cbn, frag-major bf16 cbt, f32 cbT, zero hist/count/slots ----
__global__ __launch_bounds__(256) void vq_prep(const float* __restrict__ cb,
                                               char* __restrict__ ws,
                                               char* __restrict__ cbt,
                                               float* __restrict__ cbT,
                                               float* __restrict__ fslots) {
    __shared__ float red[256];
    const int t = threadIdx.x;
    const int k = blockIdx.x * 256 + t;

    float cv[64];
#pragma unroll
    for (int d = 0; d < DIM; ++d) cv[d] = cb[d * NCODE + k];

    float s = 0.f;
#pragma unroll
    for (int d = 0; d < DIM; ++d) s = fmaf(cv[d], cv[d], s);

    ((float*)(ws + WSO_CBN))[k] = s;
    ((float*)(ws + WSO_HIST))[k] = 0.f;
    if (blockIdx.x == 0) fslots[t] = 0.f;   // zero the 256 loss slots each launch

    unsigned short hi[64], lo[64];
#pragma unroll
    for (int d = 0; d < DIM; ++d) {
        unsigned short h = f2bf(cv[d]);
        float hf = __uint_as_float(((unsigned)h) << 16);
        hi[d] = h;
        lo[d] = f2bf(cv[d] - hf);
    }

    const int c = k >> 6, cc = k & 63, wv = cc >> 4, col = cc & 15;
    char* base = cbt + (size_t)(c * 4 + wv) * 4096;
#pragma unroll
    for (int g = 0; g < 4; ++g) {
        bf16x8 h0v, h1v, l0v, l1v;
#pragma unroll
        for (int e = 0; e < 8; ++e) {
            h0v[e] = (short)hi[g * 8 + e];
            h1v[e] = (short)hi[32 + g * 8 + e];
            l0v[e] = (short)lo[g * 8 + e];
            l1v[e] = (short)lo[32 + g * 8 + e];
        }
        const int off = (g * 16 + col) * 16;
        *(bf16x8*)(base + off)        = h0v;
        *(bf16x8*)(base + 1024 + off) = h1v;
        *(bf16x8*)(base + 2048 + off) = l0v;
        *(bf16x8*)(base + 3072 + off) = l1v;
    }

#pragma unroll
    for (int j = 0; j < 16; ++j) {
        float4 v = {cv[4 * j], cv[4 * j + 1], cv[4 * j + 2], cv[4 * j + 3]};
        *(float4*)(cbT + (size_t)k * 64 + 4 * j) = v;
    }

    red[t] = s;
    __syncthreads();
    for (int m = 128; m > 0; m >>= 1) {
        if (t < m) red[t] = fmaxf(red[t], red[t + m]);
        __syncthreads();
    }
    if (t == 0) {
        ((float*)(ws + WSO_MAX4))[blockIdx.x] = red[0];
        if (blockIdx.x == 0) *(int*)(ws + WSO_COUNT) = 0;
    }
}

// ---- kernel 1: double-bf16 MFMA distances, barrier-free hot loop; block-agg count atomic ----
__global__ __launch_bounds__(256, 2) void vq_mfma(const float* __restrict__ x,
                                                  const char* __restrict__ cbt,
                                                  char* __restrict__ ws,
                                                  unsigned short* __restrict__ list,
                                                  float* __restrict__ out_idx) {
    __shared__ __align__(16) char sm[20736];
    char*  bX    = sm;
    float* cbn_s = (float*)(sm + 16384);
    float* xx_s  = (float*)(sm + 20480);
    float* R1    = (float*)sm;
    float* R2v   = R1 + 256;
    int*   RIv   = (int*)(R2v + 256);
    int*   cntL  = (int*)(sm + 8192);     // 4 ints, overlays dead bX region

    const int t = threadIdx.x, w = t >> 6, lane = t & 63;
    const int r0 = blockIdx.x * 64;

    const float* mb4 = (const float*)(ws + WSO_MAX4);
    const float maxcbn = fmaxf(fmaxf(mb4[0], mb4[1]), fmaxf(mb4[2], mb4[3]));

    gload16((const char*)(ws + WSO_CBN) + ((size_t)w * 64 + lane) * 16, (char*)cbn_s + w * 1024);

    {
        const int row = t >> 2, q = t & 3;
        const float4* xp = (const float4*)(x + (size_t)(r0 + row) * DIM + q * 16);
        float4 v0 = xp[0], v1 = xp[1], v2 = xp[2], v3 = xp[3];
        float p = 0.f;
        p = fmaf(v0.x, v0.x, p); p = fmaf(v0.y, v0.y, p); p = fmaf(v0.z, v0.z, p); p = fmaf(v0.w, v0.w, p);
        p = fmaf(v1.x, v1.x, p); p = fmaf(v1.y, v1.y, p); p = fmaf(v1.z, v1.z, p); p = fmaf(v1.w, v1.w, p);
        p = fmaf(v2.x, v2.x, p); p = fmaf(v2.y, v2.y, p); p = fmaf(v2.z, v2.z, p); p = fmaf(v2.w, v2.w, p);
        p = fmaf(v3.x, v3.x, p); p = fmaf(v3.y, v3.y, p); p = fmaf(v3.z, v3.z, p); p = fmaf(v3.w, v3.w, p);
        p += __shfl_xor(p, 1);
        p += __shfl_xor(p, 2);
        if (q == 0) xx_s[row] = p;

        float hv[16] = {v0.x, v0.y, v0.z, v0.w, v1.x, v1.y, v1.z, v1.w,
                        v2.x, v2.y, v2.z, v2.w, v3.x, v3.y, v3.z, v3.w};
        bf16x8 ph[2], pl[2];
#pragma unroll
        for (int h = 0; h < 2; ++h)
#pragma unroll
            for (int e = 0; e < 8; ++e) {
                float v = hv[h * 8 + e];
                unsigned short hb = f2bf(v);
                float hf = __uint_as_float(((unsigned)hb) << 16);
                ph[h][e] = (short)hb;
                pl[h][e] = (short)f2bf(v - hf);
            }
        const int sw = row & 7;
        char* base = bX + row * 256;
#pragma unroll
        for (int h = 0; h < 2; ++h) {
            int s3 = (2 * q + h) ^ sw;
            *(bf16x8*)(base + (s3 & 7) * 16)        = ph[h];
            *(bf16x8*)(base + (8 | (s3 & 7)) * 16)  = pl[h];
        }
    }
    __syncthreads();

    bf16x8 afh[4][2], afl[4][2];
#pragma unroll
    for (int rt = 0; rt < 4; ++rt)
#pragma unroll
        for (int kt = 0; kt < 2; ++kt) {
            int row = rt * 16 + (lane & 15);
            int s3 = ((kt * 4 + (lane >> 4)) ^ (row & 7)) & 7;
            afh[rt][kt] = *(const bf16x8*)(bX + row * 256 + s3 * 16);
            afl[rt][kt] = *(const bf16x8*)(bX + row * 256 + (8 | s3) * 16);
        }

    const int cl = w * 16 + (lane & 15);

    float m1[16], m2[16];
    int   mi[16];
#pragma unroll
    for (int s = 0; s < 16; ++s) { m1[s] = 3.4e38f; m2[s] = 3.4e38f; mi[s] = 0; }

    const char* pc = cbt + (size_t)w * 4096 + (size_t)lane * 16;

    bf16x8 bh0 = *(const bf16x8*)(pc);
    bf16x8 bh1 = *(const bf16x8*)(pc + 1024);
    bf16x8 bl0 = *(const bf16x8*)(pc + 2048);
    bf16x8 bl1 = *(const bf16x8*)(pc + 3072);

#pragma unroll 1
    for (int c = 0; c < 16; ++c) {
        const char* np = pc + 16384;
        bf16x8 nh0 = *(const bf16x8*)(np);
        bf16x8 nh1 = *(const bf16x8*)(np + 1024);
        bf16x8 nl0 = *(const bf16x8*)(np + 2048);
        bf16x8 nl1 = *(const bf16x8*)(np + 3072);

        const int kg = c * 64 + cl;
        const float cbnv = cbn_s[kg];

#pragma unroll
        for (int rt = 0; rt < 4; ++rt) {
            f32x4 z = {0.f, 0.f, 0.f, 0.f};
            z = __builtin_amdgcn_mfma_f32_16x16x32_bf16(afh[rt][0], bh0, z, 0, 0, 0);
            z = __builtin_amdgcn_mfma_f32_16x16x32_bf16(afh[rt][1], bh1, z, 0, 0, 0);
            z = __builtin_amdgcn_mfma_f32_16x16x32_bf16(afl[rt][0], bh0, z, 0, 0, 0);
            z = __builtin_amdgcn_mfma_f32_16x16x32_bf16(afl[rt][1], bh1, z, 0, 0, 0);
            z = __builtin_amdgcn_mfma_f32_16x16x32_bf16(afh[rt][0], bl0, z, 0, 0, 0);
            z = __builtin_amdgcn_mfma_f32_16x16x32_bf16(afh[rt][1], bl1, z, 0, 0, 0);
#pragma unroll
            for (int v = 0; v < 4; ++v) {
                const int s = rt * 4 + v;
                float dd = fmaf(-2.f, z[v], cbnv);
                bool lt = dd < m1[s];
                m2[s] = fminf(m2[s], fmaxf(m1[s], dd));
                m1[s] = fminf(m1[s], dd);
                mi[s] = lt ? kg : mi[s];
            }
        }
        pc = np;
        bh0 = nh0; bh1 = nh1; bl0 = nl0; bl1 = nl1;
    }

#pragma unroll
    for (int m = 1; m <= 8; m <<= 1) {
#pragma unroll
        for (int s = 0; s < 16; ++s) {
            float o1 = __shfl_xor(m1[s], m);
            float o2 = __shfl_xor(m2[s], m);
            int   oi = __shfl_xor(mi[s], m);
            float nm2 = fminf(fminf(m2[s], o2), fmaxf(m1[s], o1));
            bool tk = (o1 < m1[s]) || (o1 == m1[s] && oi < mi[s]);
            m1[s] = fminf(m1[s], o1);
            mi[s] = tk ? oi : mi[s];
            m2[s] = nm2;
        }
    }
    __syncthreads();
    if ((lane & 15) == 0) {
        const int gq = lane >> 4;
#pragma unroll
        for (int s = 0; s < 16; ++s) {
            const int row = (s >> 2) * 16 + gq * 4 + (s & 3);
            R1[row * 4 + w]  = m1[s];
            R2v[row * 4 + w] = m2[s];
            RIv[row * 4 + w] = mi[s];
        }
    }
    __syncthreads();

    bool flag = false;
    int  rr = 0;
    {
        const int row = t >> 2, q = t & 3;
        float a1 = R1[row * 4 + q];
        float A2 = R2v[row * 4 + q];
        int   ai = RIv[row * 4 + q];
#pragma unroll
        for (int m = 1; m <= 2; m <<= 1) {
            float o1 = __shfl_xor(a1, m);
            float o2 = __shfl_xor(A2, m);
            int   oi = __shfl_xor(ai, m);
            float nm2 = fminf(fminf(A2, o2), fmaxf(a1, o1));
            bool tk = (o1 < a1) || (o1 == a1 && oi < ai);
            a1 = fminf(a1, o1);
            ai = tk ? oi : ai;
            A2 = nm2;
        }
        if (q == 0) {
            const int r = r0 + row;
            out_idx[r] = (float)ai;
            const float Bv = 1.5e-4f * sqrtf(xx_s[row] * maxcbn) + 2e-3f;
            flag = (A2 - a1 <= 2.f * Bv);
            rr = r;
        }
    }
    // block-aggregated list append: one blocking atomic per block (if any flags)
    unsigned long long mk = __ballot(flag);
    const int wcnt = __popcll(mk);
    if (lane == 0) cntL[w] = wcnt;
    __syncthreads();
    if (t == 0) {
        int c0 = cntL[0], c1 = cntL[1], c2 = cntL[2], c3 = cntL[3];
        int tot = c0 + c1 + c2 + c3;
        int base = 0;
        if (tot) base = atomicAdd((int*)(ws + WSO_COUNT), tot);
        cntL[0] = base;
        cntL[1] = base + c0;
        cntL[2] = base + c0 + c1;
        cntL[3] = base + c0 + c1 + c2;
    }
    __syncthreads();
    if (flag) {
        const int off = __popcll(mk & ((1ull << lane) - 1ull));
        list[cntL[w] + off] = (unsigned short)rr;
    }
}

// ---- kernel 2: refine v3 (R12 verbatim) ----
__global__ void vq_refine(const float* __restrict__ x,
                          const float* __restrict__ cb,
                          const char* __restrict__ ws,
                          const unsigned short* __restrict__ list,
                          float* __restrict__ out_idx) {
    const int N = *(const int*)(ws + WSO_COUNT);
    const float* cbn = (const float*)(ws + WSO_CBN);
    __shared__ float rowx[4][64];
    const int t = threadIdx.x, w = t >> 6, lane = t & 63;

    for (int base = blockIdx.x * 4; base < N; base += (int)gridDim.x * 4) {
        const int ii = base + w;
        const bool valid = ii < N;
        const int r = valid ? (int)list[ii] : (int)list[0];

        __syncthreads();
        const float xv = x[(size_t)r * DIM + lane];
        rowx[w][lane] = xv;
        float p = xv * xv;
#pragma unroll
        for (int m = 1; m < 64; m <<= 1) p += __shfl_xor(p, m);
        const float xx = p;
        __syncthreads();

        float xr[64];
#pragma unroll
        for (int d = 0; d < 64; ++d) xr[d] = rowx[w][d];

        float bd = 3.4e38f;
        int   bk = 0;
        for (int kb = 0; kb < NCODE; kb += 64) {
            float d0 = 0.f, d1 = 0.f, d2 = 0.f, d3 = 0.f;
            const float* cp = cb + kb + lane;
#pragma unroll
            for (int d = 0; d < 64; d += 4) {
                d0 = fmaf(xr[d + 0], cp[(d + 0) * NCODE], d0);
                d1 = fmaf(xr[d + 1], cp[(d + 1) * NCODE], d1);
                d2 = fmaf(xr[d + 2], cp[(d + 2) * NCODE], d2);
                d3 = fmaf(xr[d + 3], cp[(d + 3) * NCODE], d3);
            }
            const float dot = (d0 + d1) + (d2 + d3);
            const float dist = fmaf(-2.f, dot, xx) + cbn[kb + lane];
            const int k = kb + lane;
            if (dist < bd) { bd = dist; bk = k; }
        }
#pragma unroll
        for (int m = 1; m < 64; m <<= 1) {
            float od = __shfl_xor(bd, m);
            int   ok = __shfl_xor(bk, m);
            if (od < bd || (od == bd && ok < bk)) { bd = od; bk = ok; }
        }
        if (lane == 0 && valid) out_idx[r] = (float)bk;
    }
}

// ---- kernel 3a: epilogue E1 — cbT gather; loss -> per-block reduce + slotted atomic ----
__global__ __launch_bounds__(256) void vq_epi_main(const float* __restrict__ x,
                                                   const float* __restrict__ cbT,
                                                   const float* __restrict__ idx_f,
                                                   float* __restrict__ out_xq,
                                                   char* __restrict__ ws,
                                                   float* __restrict__ fslots) {
    __shared__ float lred[4];
    const int t = threadIdx.x;
    const int r_lin = blockIdx.x * 32 + (t >> 3);        // 0..64511
    const int r = (r_lin < 1024) ? r_lin : r_lin + 1024; // skip cbT rows
    const int q8 = t & 7;
    const int k = (int)idx_f[r];

    const float4* cp = (const float4*)(cbT + (size_t)k * 64 + q8 * 8);
    const float4* xp = (const float4*)(x + (size_t)r * DIM + q8 * 8);
    float4* op = (float4*)(out_xq + (size_t)r * DIM + q8 * 8);

    float4 c0 = cp[0], c1 = cp[1];
    float4 x0 = xp[0], x1 = xp[1];
    float e0 = c0.x - x0.x, e1 = c0.y - x0.y, e2 = c0.z - x0.z, e3 = c0.w - x0.w;
    float e4 = c1.x - x1.x, e5 = c1.y - x1.y, e6 = c1.z - x1.z, e7 = c1.w - x1.w;
    float4 o0, o1;
    o0.x = x0.x + e0; o0.y = x0.y + e1; o0.z = x0.z + e2; o0.w = x0.w + e3;
    o1.x = x1.x + e4; o1.y = x1.y + e5; o1.z = x1.z + e6; o1.w = x1.w + e7;
    op[0] = o0; op[1] = o1;

    float lsum = 0.f;
    lsum = fmaf(e0, e0, lsum); lsum = fmaf(e1, e1, lsum);
    lsum = fmaf(e2, e2, lsum); lsum = fmaf(e3, e3, lsum);
    lsum = fmaf(e4, e4, lsum); lsum = fmaf(e5, e5, lsum);
    lsum = fmaf(e6, e6, lsum); lsum = fmaf(e7, e7, lsum);

    if (q8 == 0) atomicAdd((float*)(ws + WSO_HIST) + k, 1.0f);
#pragma unroll
    for (int off = 1; off < 64; off <<= 1) lsum += __shfl_xor(lsum, off);
    if ((t & 63) == 0) lred[t >> 6] = lsum;
    __syncthreads();
    if (t == 0)
        atomicAdd(&fslots[blockIdx.x & 255], (lred[0] + lred[1]) + (lred[2] + lred[3]));
}

// ---- kernel 3b: epilogue E2 — rows 1024..2047, direct-cb gather; slotted loss ----
__global__ __launch_bounds__(256) void vq_epi_tail(const float* __restrict__ x,
                                                   const float* __restrict__ cb,
                                                   const float* __restrict__ idx_f,
                                                   float* __restrict__ out_xq,
                                                   char* __restrict__ ws,
                                                   float* __restrict__ fslots) {
    __shared__ float lred[4];
    const int t = threadIdx.x;
    const int row = 1024 + blockIdx.x * 64 + (t >> 2), q = t & 3;
    const int k = (int)idx_f[row];
    const float4* xp = (const float4*)(x + (size_t)row * DIM + q * 16);
    float4* op = (float4*)(out_xq + (size_t)row * DIM + q * 16);
    float lsum = 0.f;
#pragma unroll
    for (int j = 0; j < 4; ++j) {
        float4 xv = xp[j];
        const int d0 = q * 16 + 4 * j;
        float q0 = cb[(d0 + 0) * NCODE + k];
        float q1 = cb[(d0 + 1) * NCODE + k];
        float q2 = cb[(d0 + 2) * NCODE + k];
        float q3 = cb[(d0 + 3) * NCODE + k];
        float e0 = q0 - xv.x, e1 = q1 - xv.y, e2 = q2 - xv.z, e3 = q3 - xv.w;
        float4 o;
        o.x = xv.x + e0; o.y = xv.y + e1; o.z = xv.z + e2; o.w = xv.w + e3;
        op[j] = o;
        lsum = fmaf(e0, e0, lsum); lsum = fmaf(e1, e1, lsum);
        lsum = fmaf(e2, e2, lsum); lsum = fmaf(e3, e3, lsum);
    }
    if (q == 0) atomicAdd((float*)(ws + WSO_HIST) + k, 1.0f);
#pragma unroll
    for (int off = 1; off < 64; off <<= 1) lsum += __shfl_xor(lsum, off);
    if ((t & 63) == 0) lred[t >> 6] = lsum;
    __syncthreads();
    if (t == 0)
        atomicAdd(&fslots[blockIdx.x], (lred[0] + lred[1]) + (lred[2] + lred[3]));
}

// ---- kernel 4: final — reduce 256 loss slots, then overwrite region with EMA freq ----
__global__ __launch_bounds__(1024) void vq_final(const float* __restrict__ cf,
                                                 const char* __restrict__ ws,
                                                 float* __restrict__ fslots,
                                                 float* __restrict__ out_loss,
                                                 float* __restrict__ out_freq) {
    __shared__ float red[256];
    const int t = threadIdx.x;
    if (t < 256) red[t] = fslots[t];
    __syncthreads();
    for (int m = 128; m > 0; m >>= 1) {
        if (t < m) red[t] += red[t + m];
        __syncthreads();
    }
    if (t == 0) {
        float m = red[0] / 4194304.0f;
        out_loss[0] = m + m;
    }
    __syncthreads();   // slot reads done before freq overwrite
    out_freq[t] = 0.95f * cf[t] + 0.05f * ((const float*)(ws + WSO_HIST))[t];
}

extern "C" void kernel_launch(void* const* d_in, const int* in_sizes, int n_in,
                              void* d_out, int out_size, void* d_ws, size_t ws_size,
                              hipStream_t stream) {
    const float* x  = (const float*)d_in[0];   // [16,4096,64]
    const float* cb = (const float*)d_in[1];   // [64,1024]
    const float* cf = (const float*)d_in[2];   // [1024]

    float* out      = (float*)d_out;
    float* out_xq   = out;                     // 4,194,304 floats
    float* out_idx  = out + 4194304;           // 65,536
    float* out_loss = out + 4194304 + 65536;   // 1
    float* out_freq = out_loss + 1;            // 1024 (doubles as loss slots pre-final)

    char* ws = (char*)d_ws;                    // 8,256 bytes used

    char*           cbt  = (char*)d_out;                               // 262,144 B
    float*          cbT  = (float*)((char*)d_out + 262144);            // 262,144 B
    unsigned short* list = (unsigned short*)((char*)d_out + 524288);   // 131,072 B
    float*          fslots = out_freq;                                 // 256 slots

    vq_prep    <<<4,    256,  0, stream>>>(cb, ws, cbt, cbT, fslots);
    vq_mfma    <<<1024, 256,  0, stream>>>(x, cbt, ws, list, out_idx);
    vq_refine  <<<2048, 256,  0, stream>>>(x, cb, ws, list, out_idx);
    vq_epi_main<<<2016, 256,  0, stream>>>(x, cbT, out_idx, out_xq, ws, fslots);
    vq_epi_tail<<<16,   256,  0, stream>>>(x, cb, out_idx, out_xq, ws, fslots);
    vq_final   <<<1,    1024, 0, stream>>>(cf, ws, fslots, out_loss, out_freq);
}

// Round 16
// 135.494 us; speedup vs baseline: 1.4988x; 1.1313x over previous
//
#include <hip/hip_runtime.h>

#define DIM 64
#define NCODE 1024

typedef __attribute__((ext_vector_type(8))) short bf16x8;
typedef __attribute__((ext_vector_type(4))) float f32x4;

// ---- small ws (8.3 KB) ----
#define WSO_HIST  0        // float[1024]
#define WSO_LOSS  4096     // float (unused now)
#define WSO_COUNT 4100     // int
#define WSO_MAX4  4112     // float[4]
#define WSO_CBN   4160     // float[1024]

// ---- big scratch in d_out's out_xq region ----
// cbt (fragment-major bf16 hi/lo) @0       (262144 B)
// cbT (f32 [code][64])            @262144  (262144 B)
// list (u16 flagged rows)         @524288  (131072 B)
// loss slots: out_freq region (256 floats) — zeroed by prep, slot-atomics by E1/E2,
// consumed+overwritten by final.

__device__ __forceinline__ unsigned short f2bf(float f) {
    unsigned u = __float_as_uint(f);
    unsigned r = (u + 0x7FFFu + ((u >> 16) & 1u)) >> 16;   // RNE
    return (unsigned short)r;
}

__device__ __forceinline__ void gload16(const void* g, void* l) {
    __builtin_amdgcn_global_load_lds(
        (const __attribute__((address_space(1))) unsigned int*)g,
        (__attribute__((address_space(3))) unsigned int*)l, 16, 0, 0);
}

// ---- kernel 0: prep (4 x 256) ----
__global__ __launch_bounds__(256) void vq_prep(const float* __restrict__ cb,
                                               char* __restrict__ ws,
                                               char* __restrict__ cbt,
                                               float* __restrict__ cbT,
                                               float* __restrict__ fslots) {
    __shared__ float red[256];
    const int t = threadIdx.x;
    const int k = blockIdx.x * 256 + t;

    float cv[64];
#pragma unroll
    for (int d = 0; d < DIM; ++d) cv[d] = cb[d * NCODE + k];

    float s = 0.f;
#pragma unroll
    for (int d = 0; d < DIM; ++d) s = fmaf(cv[d], cv[d], s);

    ((float*)(ws + WSO_CBN))[k] = s;
    ((float*)(ws + WSO_HIST))[k] = 0.f;
    if (blockIdx.x == 0) fslots[t] = 0.f;

    unsigned short hi[64], lo[64];
#pragma unroll
    for (int d = 0; d < DIM; ++d) {
        unsigned short h = f2bf(cv[d]);
        float hf = __uint_as_float(((unsigned)h) << 16);
        hi[d] = h;
        lo[d] = f2bf(cv[d] - hf);
    }

    const int c = k >> 6, cc = k & 63, wv = cc >> 4, col = cc & 15;
    char* base = cbt + (size_t)(c * 4 + wv) * 4096;
#pragma unroll
    for (int g = 0; g < 4; ++g) {
        bf16x8 h0v, h1v, l0v, l1v;
#pragma unroll
        for (int e = 0; e < 8; ++e) {
            h0v[e] = (short)hi[g * 8 + e];
            h1v[e] = (short)hi[32 + g * 8 + e];
            l0v[e] = (short)lo[g * 8 + e];
            l1v[e] = (short)lo[32 + g * 8 + e];
        }
        const int off = (g * 16 + col) * 16;
        *(bf16x8*)(base + off)        = h0v;
        *(bf16x8*)(base + 1024 + off) = h1v;
        *(bf16x8*)(base + 2048 + off) = l0v;
        *(bf16x8*)(base + 3072 + off) = l1v;
    }

#pragma unroll
    for (int j = 0; j < 16; ++j) {
        float4 v = {cv[4 * j], cv[4 * j + 1], cv[4 * j + 2], cv[4 * j + 3]};
        *(float4*)(cbT + (size_t)k * 64 + 4 * j) = v;
    }

    red[t] = s;
    __syncthreads();
    for (int m = 128; m > 0; m >>= 1) {
        if (t < m) red[t] = fmaxf(red[t], red[t + m]);
        __syncthreads();
    }
    if (t == 0) {
        ((float*)(ws + WSO_MAX4))[blockIdx.x] = red[0];
        if (blockIdx.x == 0) *(int*)(ws + WSO_COUNT) = 0;
    }
}

// ---- kernel 1: MFMA distances; wave = (rowhalf x codetile) for low VGPR/occupancy ----
// 4 waves: rh=w&1 rows [rh*32,+32), ct=w>>1 code tile. 32 chunks of 32 codes;
// per chunk: 12 MFMA/wave. A-frags 32 VGPR, B cur+next 32, minima 24 -> need ~125.
// (256,3): cap 168 >= need -> no spill (R11's spill was need~196 > 168).
__global__ __launch_bounds__(256, 3) void vq_mfma(const float* __restrict__ x,
                                                  const char* __restrict__ cbt,
                                                  char* __restrict__ ws,
                                                  unsigned short* __restrict__ list,
                                                  float* __restrict__ out_idx) {
    __shared__ __align__(16) char sm[20736];
    char*  bX    = sm;
    float* cbn_s = (float*)(sm + 16384);
    float* xx_s  = (float*)(sm + 20480);
    float* R1    = (float*)sm;            // overlays bX post-loop: 128 floats
    float* R2v   = R1 + 128;
    int*   RIv   = (int*)(R2v + 128);
    int*   cntL  = (int*)(sm + 8192);

    const int t = threadIdx.x, w = t >> 6, lane = t & 63;
    const int rh = w & 1, ct = w >> 1;
    const int r0 = blockIdx.x * 64;

    const float* mb4 = (const float*)(ws + WSO_MAX4);
    const float maxcbn = fmaxf(fmaxf(mb4[0], mb4[1]), fmaxf(mb4[2], mb4[3]));

    gload16((const char*)(ws + WSO_CBN) + ((size_t)w * 64 + lane) * 16, (char*)cbn_s + w * 1024);

    // --- stage bX (hi/lo bf16, XOR-swizzled) + xx (all 4 waves, 64 rows) ---
    {
        const int row = t >> 2, q = t & 3;
        const float4* xp = (const float4*)(x + (size_t)(r0 + row) * DIM + q * 16);
        float4 v0 = xp[0], v1 = xp[1], v2 = xp[2], v3 = xp[3];
        float p = 0.f;
        p = fmaf(v0.x, v0.x, p); p = fmaf(v0.y, v0.y, p); p = fmaf(v0.z, v0.z, p); p = fmaf(v0.w, v0.w, p);
        p = fmaf(v1.x, v1.x, p); p = fmaf(v1.y, v1.y, p); p = fmaf(v1.z, v1.z, p); p = fmaf(v1.w, v1.w, p);
        p = fmaf(v2.x, v2.x, p); p = fmaf(v2.y, v2.y, p); p = fmaf(v2.z, v2.z, p); p = fmaf(v2.w, v2.w, p);
        p = fmaf(v3.x, v3.x, p); p = fmaf(v3.y, v3.y, p); p = fmaf(v3.z, v3.z, p); p = fmaf(v3.w, v3.w, p);
        p += __shfl_xor(p, 1);
        p += __shfl_xor(p, 2);
        if (q == 0) xx_s[row] = p;

        float hv[16] = {v0.x, v0.y, v0.z, v0.w, v1.x, v1.y, v1.z, v1.w,
                        v2.x, v2.y, v2.z, v2.w, v3.x, v3.y, v3.z, v3.w};
        bf16x8 ph[2], pl[2];
#pragma unroll
        for (int h = 0; h < 2; ++h)
#pragma unroll
            for (int e = 0; e < 8; ++e) {
                float v = hv[h * 8 + e];
                unsigned short hb = f2bf(v);
                float hf = __uint_as_float(((unsigned)hb) << 16);
                ph[h][e] = (short)hb;
                pl[h][e] = (short)f2bf(v - hf);
            }
        const int sw = row & 7;
        char* base = bX + row * 256;
#pragma unroll
        for (int h = 0; h < 2; ++h) {
            int s3 = (2 * q + h) ^ sw;
            *(bf16x8*)(base + (s3 & 7) * 16)        = ph[h];
            *(bf16x8*)(base + (8 | (s3 & 7)) * 16)  = pl[h];
        }
    }
    __syncthreads();

    // --- A fragments: 32 rows (rh half), rt in {0,1} ---
    bf16x8 afh[2][2], afl[2][2];
#pragma unroll
    for (int rt = 0; rt < 2; ++rt)
#pragma unroll
        for (int kt = 0; kt < 2; ++kt) {
            int row = rh * 32 + rt * 16 + (lane & 15);
            int s3 = ((kt * 4 + (lane >> 4)) ^ (row & 7)) & 7;
            afh[rt][kt] = *(const bf16x8*)(bX + row * 256 + s3 * 16);
            afl[rt][kt] = *(const bf16x8*)(bX + row * 256 + (8 | s3) * 16);
        }

    const int cl = ct * 16 + (lane & 15);   // code within a 32-chunk

    float m1[8], m2[8];
    int   mi[8];
#pragma unroll
    for (int s = 0; s < 8; ++s) { m1[s] = 3.4e38f; m2[s] = 3.4e38f; mi[s] = 0; }

    // segment for (chunk32 c2, tile ct) = (c2*2 + ct)*4096 ; next chunk at +8192
    const char* pc = cbt + (size_t)ct * 4096 + (size_t)lane * 16;

    bf16x8 bh0 = *(const bf16x8*)(pc);
    bf16x8 bh1 = *(const bf16x8*)(pc + 1024);
    bf16x8 bl0 = *(const bf16x8*)(pc + 2048);
    bf16x8 bl1 = *(const bf16x8*)(pc + 3072);

#pragma unroll 1
    for (int c2 = 0; c2 < 32; ++c2) {
        const char* np = pc + 8192;
        bf16x8 nh0 = *(const bf16x8*)(np);
        bf16x8 nh1 = *(const bf16x8*)(np + 1024);
        bf16x8 nl0 = *(const bf16x8*)(np + 2048);
        bf16x8 nl1 = *(const bf16x8*)(np + 3072);

        const int kg = c2 * 32 + cl;
        const float cbnv = cbn_s[kg];

#pragma unroll
        for (int rt = 0; rt < 2; ++rt) {
            f32x4 z = {0.f, 0.f, 0.f, 0.f};
            z = __builtin_amdgcn_mfma_f32_16x16x32_bf16(afh[rt][0], bh0, z, 0, 0, 0);
            z = __builtin_amdgcn_mfma_f32_16x16x32_bf16(afh[rt][1], bh1, z, 0, 0, 0);
            z = __builtin_amdgcn_mfma_f32_16x16x32_bf16(afl[rt][0], bh0, z, 0, 0, 0);
            z = __builtin_amdgcn_mfma_f32_16x16x32_bf16(afl[rt][1], bh1, z, 0, 0, 0);
            z = __builtin_amdgcn_mfma_f32_16x16x32_bf16(afh[rt][0], bl0, z, 0, 0, 0);
            z = __builtin_amdgcn_mfma_f32_16x16x32_bf16(afh[rt][1], bl1, z, 0, 0, 0);
#pragma unroll
            for (int v = 0; v < 4; ++v) {
                const int s = rt * 4 + v;
                float dd = fmaf(-2.f, z[v], cbnv);
                bool lt = dd < m1[s];
                m2[s] = fminf(m2[s], fmaxf(m1[s], dd));
                m1[s] = fminf(m1[s], dd);
                mi[s] = lt ? kg : mi[s];
            }
        }
        pc = np;
        bh0 = nh0; bh1 = nh1; bl0 = nl0; bl1 = nl1;
    }

    // --- butterfly reduce over lane&15 (same row, disjoint codes) ---
#pragma unroll
    for (int m = 1; m <= 8; m <<= 1) {
#pragma unroll
        for (int s = 0; s < 8; ++s) {
            float o1 = __shfl_xor(m1[s], m);
            float o2 = __shfl_xor(m2[s], m);
            int   oi = __shfl_xor(mi[s], m);
            float nm2 = fminf(fminf(m2[s], o2), fmaxf(m1[s], o1));
            bool tk = (o1 < m1[s]) || (o1 == m1[s] && oi < mi[s]);
            m1[s] = fminf(m1[s], o1);
            mi[s] = tk ? oi : mi[s];
            m2[s] = nm2;
        }
    }
    __syncthreads();   // bX reads done before overlay write
    // --- stage B: one writer per (row, ct): R[row*2 + ct] ---
    if ((lane & 15) == 0) {
        const int gq = lane >> 4;
#pragma unroll
        for (int s = 0; s < 8; ++s) {
            const int row = rh * 32 + (s >> 2) * 16 + gq * 4 + (s & 3);
            R1[row * 2 + ct]  = m1[s];
            R2v[row * 2 + ct] = m2[s];
            RIv[row * 2 + ct] = mi[s];
        }
    }
    __syncthreads();

    bool flag = false;
    int  rr = 0;
    if (t < 128) {
        const int row = t >> 1, q = t & 1;
        float a1 = R1[row * 2 + q];
        float A2 = R2v[row * 2 + q];
        int   ai = RIv[row * 2 + q];
        {
            float o1 = __shfl_xor(a1, 1);
            float o2 = __shfl_xor(A2, 1);
            int   oi = __shfl_xor(ai, 1);
            float nm2 = fminf(fminf(A2, o2), fmaxf(a1, o1));
            bool tk = (o1 < a1) || (o1 == a1 && oi < ai);
            a1 = fminf(a1, o1);
            ai = tk ? oi : ai;
            A2 = nm2;
        }
        if (q == 0) {
            const int r = r0 + row;
            out_idx[r] = (float)ai;
            const float Bv = 1.5e-4f * sqrtf(xx_s[row] * maxcbn) + 2e-3f;
            flag = (A2 - a1 <= 2.f * Bv);
            rr = r;
        }
    }
    // block-aggregated list append
    unsigned long long mk = __ballot(flag);
    const int wcnt = __popcll(mk);
    if (lane == 0) cntL[w] = wcnt;
    __syncthreads();
    if (t == 0) {
        int c0 = cntL[0], c1 = cntL[1], c2 = cntL[2], c3 = cntL[3];
        int tot = c0 + c1 + c2 + c3;
        int base = 0;
        if (tot) base = atomicAdd((int*)(ws + WSO_COUNT), tot);
        cntL[0] = base;
        cntL[1] = base + c0;
        cntL[2] = base + c0 + c1;
        cntL[3] = base + c0 + c1 + c2;
    }
    __syncthreads();
    if (flag) {
        const int off = __popcll(mk & ((1ull << lane) - 1ull));
        list[cntL[w] + off] = (unsigned short)rr;
    }
}

// ---- kernel 2: refine v3 (R12 verbatim) ----
__global__ void vq_refine(const float* __restrict__ x,
                          const float* __restrict__ cb,
                          const char* __restrict__ ws,
                          const unsigned short* __restrict__ list,
                          float* __restrict__ out_idx) {
    const int N = *(const int*)(ws + WSO_COUNT);
    const float* cbn = (const float*)(ws + WSO_CBN);
    __shared__ float rowx[4][64];
    const int t = threadIdx.x, w = t >> 6, lane = t & 63;

    for (int base = blockIdx.x * 4; base < N; base += (int)gridDim.x * 4) {
        const int ii = base + w;
        const bool valid = ii < N;
        const int r = valid ? (int)list[ii] : (int)list[0];

        __syncthreads();
        const float xv = x[(size_t)r * DIM + lane];
        rowx[w][lane] = xv;
        float p = xv * xv;
#pragma unroll
        for (int m = 1; m < 64; m <<= 1) p += __shfl_xor(p, m);
        const float xx = p;
        __syncthreads();

        float xr[64];
#pragma unroll
        for (int d = 0; d < 64; ++d) xr[d] = rowx[w][d];

        float bd = 3.4e38f;
        int   bk = 0;
        for (int kb = 0; kb < NCODE; kb += 64) {
            float d0 = 0.f, d1 = 0.f, d2 = 0.f, d3 = 0.f;
            const float* cp = cb + kb + lane;
#pragma unroll
            for (int d = 0; d < 64; d += 4) {
                d0 = fmaf(xr[d + 0], cp[(d + 0) * NCODE], d0);
                d1 = fmaf(xr[d + 1], cp[(d + 1) * NCODE], d1);
                d2 = fmaf(xr[d + 2], cp[(d + 2) * NCODE], d2);
                d3 = fmaf(xr[d + 3], cp[(d + 3) * NCODE], d3);
            }
            const float dot = (d0 + d1) + (d2 + d3);
            const float dist = fmaf(-2.f, dot, xx) + cbn[kb + lane];
            const int k = kb + lane;
            if (dist < bd) { bd = dist; bk = k; }
        }
#pragma unroll
        for (int m = 1; m < 64; m <<= 1) {
            float od = __shfl_xor(bd, m);
            int   ok = __shfl_xor(bk, m);
            if (od < bd || (od == bd && ok < bk)) { bd = od; bk = ok; }
        }
        if (lane == 0 && valid) out_idx[r] = (float)bk;
    }
}

// ---- kernel 3a: epilogue E1 (R15 verbatim) ----
__global__ __launch_bounds__(256) void vq_epi_main(const float* __restrict__ x,
                                                   const float* __restrict__ cbT,
                                                   const float* __restrict__ idx_f,
                                                   float* __restrict__ out_xq,
                                                   char* __restrict__ ws,
                                                   float* __restrict__ fslots) {
    __shared__ float lred[4];
    const int t = threadIdx.x;
    const int r_lin = blockIdx.x * 32 + (t >> 3);
    const int r = (r_lin < 1024) ? r_lin : r_lin + 1024;
    const int q8 = t & 7;
    const int k = (int)idx_f[r];

    const float4* cp = (const float4*)(cbT + (size_t)k * 64 + q8 * 8);
    const float4* xp = (const float4*)(x + (size_t)r * DIM + q8 * 8);
    float4* op = (float4*)(out_xq + (size_t)r * DIM + q8 * 8);

    float4 c0 = cp[0], c1 = cp[1];
    float4 x0 = xp[0], x1 = xp[1];
    float e0 = c0.x - x0.x, e1 = c0.y - x0.y, e2 = c0.z - x0.z, e3 = c0.w - x0.w;
    float e4 = c1.x - x1.x, e5 = c1.y - x1.y, e6 = c1.z - x1.z, e7 = c1.w - x1.w;
    float4 o0, o1;
    o0.x = x0.x + e0; o0.y = x0.y + e1; o0.z = x0.z + e2; o0.w = x0.w + e3;
    o1.x = x1.x + e4; o1.y = x1.y + e5; o1.z = x1.z + e6; o1.w = x1.w + e7;
    op[0] = o0; op[1] = o1;

    float lsum = 0.f;
    lsum = fmaf(e0, e0, lsum); lsum = fmaf(e1, e1, lsum);
    lsum = fmaf(e2, e2, lsum); lsum = fmaf(e3, e3, lsum);
    lsum = fmaf(e4, e4, lsum); lsum = fmaf(e5, e5, lsum);
    lsum = fmaf(e6, e6, lsum); lsum = fmaf(e7, e7, lsum);

    if (q8 == 0) atomicAdd((float*)(ws + WSO_HIST) + k, 1.0f);
#pragma unroll
    for (int off = 1; off < 64; off <<= 1) lsum += __shfl_xor(lsum, off);
    if ((t & 63) == 0) lred[t >> 6] = lsum;
    __syncthreads();
    if (t == 0)
        atomicAdd(&fslots[blockIdx.x & 255], (lred[0] + lred[1]) + (lred[2] + lred[3]));
}

// ---- kernel 3b: epilogue E2 (R15 verbatim) ----
__global__ __launch_bounds__(256) void vq_epi_tail(const float* __restrict__ x,
                                                   const float* __restrict__ cb,
                                                   const float* __restrict__ idx_f,
                                                   float* __restrict__ out_xq,
                                                   char* __restrict__ ws,
                                                   float* __restrict__ fslots) {
    __shared__ float lred[4];
    const int t = threadIdx.x;
    const int row = 1024 + blockIdx.x * 64 + (t >> 2), q = t & 3;
    const int k = (int)idx_f[row];
    const float4* xp = (const float4*)(x + (size_t)row * DIM + q * 16);
    float4* op = (float4*)(out_xq + (size_t)row * DIM + q * 16);
    float lsum = 0.f;
#pragma unroll
    for (int j = 0; j < 4; ++j) {
        float4 xv = xp[j];
        const int d0 = q * 16 + 4 * j;
        float q0 = cb[(d0 + 0) * NCODE + k];
        float q1 = cb[(d0 + 1) * NCODE + k];
        float q2 = cb[(d0 + 2) * NCODE + k];
        float q3 = cb[(d0 + 3) * NCODE + k];
        float e0 = q0 - xv.x, e1 = q1 - xv.y, e2 = q2 - xv.z, e3 = q3 - xv.w;
        float4 o;
        o.x = xv.x + e0; o.y = xv.y + e1; o.z = xv.z + e2; o.w = xv.w + e3;
        op[j] = o;
        lsum = fmaf(e0, e0, lsum); lsum = fmaf(e1, e1, lsum);
        lsum = fmaf(e2, e2, lsum); lsum = fmaf(e3, e3, lsum);
    }
    if (q == 0) atomicAdd((float*)(ws + WSO_HIST) + k, 1.0f);
#pragma unroll
    for (int off = 1; off < 64; off <<= 1) lsum += __shfl_xor(lsum, off);
    if ((t & 63) == 0) lred[t >> 6] = lsum;
    __syncthreads();
    if (t == 0)
        atomicAdd(&fslots[blockIdx.x], (lred[0] + lred[1]) + (lred[2] + lred[3]));
}

// ---- kernel 4: final (R15 verbatim) ----
__global__ __launch_bounds__(1024) void vq_final(const float* __restrict__ cf,
                                                 const char* __restrict__ ws,
                                                 float* __restrict__ fslots,
                                                 float* __restrict__ out_loss,
                                                 float* __restrict__ out_freq) {
    __shared__ float red[256];
    const int t = threadIdx.x;
    if (t < 256) red[t] = fslots[t];
    __syncthreads();
    for (int m = 128; m > 0; m >>= 1) {
        if (t < m) red[t] += red[t + m];
        __syncthreads();
    }
    if (t == 0) {
        float m = red[0] / 4194304.0f;
        out_loss[0] = m + m;
    }
    __syncthreads();
    out_freq[t] = 0.95f * cf[t] + 0.05f * ((const float*)(ws + WSO_HIST))[t];
}

extern "C" void kernel_launch(void* const* d_in, const int* in_sizes, int n_in,
                              void* d_out, int out_size, void* d_ws, size_t ws_size,
                              hipStream_t stream) {
    const float* x  = (const float*)d_in[0];   // [16,4096,64]
    const float* cb = (const float*)d_in[1];   // [64,1024]
    const float* cf = (const float*)d_in[2];   // [1024]

    float* out      = (float*)d_out;
    float* out_xq   = out;                     // 4,194,304 floats
    float* out_idx  = out + 4194304;           // 65,536
    float* out_loss = out + 4194304 + 65536;   // 1
    float* out_freq = out_loss + 1;            // 1024 (doubles as loss slots pre-final)

    char* ws = (char*)d_ws;                    // 8,256 bytes used

    char*           cbt  = (char*)d_out;                               // 262,144 B
    float*          cbT  = (float*)((char*)d_out + 262144);            // 262,144 B
    unsigned short* list = (unsigned short*)((char*)d_out + 524288);   // 131,072 B
    float*          fslots = out_freq;                                 // 256 slots

    vq_prep    <<<4,    256,  0, stream>>>(cb, ws, cbt, cbT, fslots);
    vq_mfma    <<<1024, 256,  0, stream>>>(x, cbt, ws, list, out_idx);
    vq_refine  <<<2048, 256,  0, stream>>>(x, cb, ws, list, out_idx);
    vq_epi_main<<<2016, 256,  0, stream>>>(x, cbT, out_idx, out_xq, ws, fslots);
    vq_epi_tail<<<16,   256,  0, stream>>>(x, cb, out_idx, out_xq, ws, fslots);
    vq_final   <<<1,    1024, 0, stream>>>(cf, ws, fslots, out_loss, out_freq);
}

// Round 17
// 91.332 us; speedup vs baseline: 2.2235x; 1.4835x over previous
//
#include <hip/hip_runtime.h>

#define DIM 64
#define NCODE 1024

typedef __attribute__((ext_vector_type(8))) short bf16x8;
typedef __attribute__((ext_vector_type(4))) float f32x4;

// ---- small ws (8.3 KB) ----
#define WSO_SLOTS 0        // float[256] loss slots (was hist; hist is now atomic-free)
#define WSO_COUNT 4100     // int
#define WSO_MAX4  4112     // float[4]
#define WSO_CBN   4160     // float[1024]

// ---- big scratch in d_out's out_xq region ----
// cbt (fragment-major bf16 hi/lo) @0       (262144 B)
// cbT (f32 [code][64])            @262144  (262144 B)
// list (u16 flagged rows)         @524288  (131072 B) -> reused as 32 hist partials
// Order: prep -> mfma -> refine -> hist(partials into list region) ->
//        freq(read partials, write out_freq) -> E1 -> E2 -> loss.

__device__ __forceinline__ unsigned short f2bf(float f) {
    unsigned u = __float_as_uint(f);
    unsigned r = (u + 0x7FFFu + ((u >> 16) & 1u)) >> 16;   // RNE
    return (unsigned short)r;
}

__device__ __forceinline__ void gload16(const void* g, void* l) {
    __builtin_amdgcn_global_load_lds(
        (const __attribute__((address_space(1))) unsigned int*)g,
        (__attribute__((address_space(3))) unsigned int*)l, 16, 0, 0);
}

// ---- kernel 0: prep (4 x 256) ----
__global__ __launch_bounds__(256) void vq_prep(const float* __restrict__ cb,
                                               char* __restrict__ ws,
                                               char* __restrict__ cbt,
                                               float* __restrict__ cbT) {
    __shared__ float red[256];
    const int t = threadIdx.x;
    const int k = blockIdx.x * 256 + t;

    float cv[64];
#pragma unroll
    for (int d = 0; d < DIM; ++d) cv[d] = cb[d * NCODE + k];

    float s = 0.f;
#pragma unroll
    for (int d = 0; d < DIM; ++d) s = fmaf(cv[d], cv[d], s);

    ((float*)(ws + WSO_CBN))[k] = s;
    if (blockIdx.x == 0) ((float*)(ws + WSO_SLOTS))[t] = 0.f;   // zero 256 loss slots

    unsigned short hi[64], lo[64];
#pragma unroll
    for (int d = 0; d < DIM; ++d) {
        unsigned short h = f2bf(cv[d]);
        float hf = __uint_as_float(((unsigned)h) << 16);
        hi[d] = h;
        lo[d] = f2bf(cv[d] - hf);
    }

    const int c = k >> 6, cc = k & 63, wv = cc >> 4, col = cc & 15;
    char* base = cbt + (size_t)(c * 4 + wv) * 4096;
#pragma unroll
    for (int g = 0; g < 4; ++g) {
        bf16x8 h0v, h1v, l0v, l1v;
#pragma unroll
        for (int e = 0; e < 8; ++e) {
            h0v[e] = (short)hi[g * 8 + e];
            h1v[e] = (short)hi[32 + g * 8 + e];
            l0v[e] = (short)lo[g * 8 + e];
            l1v[e] = (short)lo[32 + g * 8 + e];
        }
        const int off = (g * 16 + col) * 16;
        *(bf16x8*)(base + off)        = h0v;
        *(bf16x8*)(base + 1024 + off) = h1v;
        *(bf16x8*)(base + 2048 + off) = l0v;
        *(bf16x8*)(base + 3072 + off) = l1v;
    }

#pragma unroll
    for (int j = 0; j < 16; ++j) {
        float4 v = {cv[4 * j], cv[4 * j + 1], cv[4 * j + 2], cv[4 * j + 3]};
        *(float4*)(cbT + (size_t)k * 64 + 4 * j) = v;
    }

    red[t] = s;
    __syncthreads();
    for (int m = 128; m > 0; m >>= 1) {
        if (t < m) red[t] = fmaxf(red[t], red[t + m]);
        __syncthreads();
    }
    if (t == 0) {
        ((float*)(ws + WSO_MAX4))[blockIdx.x] = red[0];
        if (blockIdx.x == 0) *(int*)(ws + WSO_COUNT) = 0;
    }
}

// ---- kernel 1: MFMA distances (R16 verbatim: wave = rowhalf x codetile) ----
__global__ __launch_bounds__(256, 3) void vq_mfma(const float* __restrict__ x,
                                                  const char* __restrict__ cbt,
                                                  char* __restrict__ ws,
                                                  unsigned short* __restrict__ list,
                                                  float* __restrict__ out_idx) {
    __shared__ __align__(16) char sm[20736];
    char*  bX    = sm;
    float* cbn_s = (float*)(sm + 16384);
    float* xx_s  = (float*)(sm + 20480);
    float* R1    = (float*)sm;
    float* R2v   = R1 + 128;
    int*   RIv   = (int*)(R2v + 128);
    int*   cntL  = (int*)(sm + 8192);

    const int t = threadIdx.x, w = t >> 6, lane = t & 63;
    const int rh = w & 1, ct = w >> 1;
    const int r0 = blockIdx.x * 64;

    const float* mb4 = (const float*)(ws + WSO_MAX4);
    const float maxcbn = fmaxf(fmaxf(mb4[0], mb4[1]), fmaxf(mb4[2], mb4[3]));

    gload16((const char*)(ws + WSO_CBN) + ((size_t)w * 64 + lane) * 16, (char*)cbn_s + w * 1024);

    {
        const int row = t >> 2, q = t & 3;
        const float4* xp = (const float4*)(x + (size_t)(r0 + row) * DIM + q * 16);
        float4 v0 = xp[0], v1 = xp[1], v2 = xp[2], v3 = xp[3];
        float p = 0.f;
        p = fmaf(v0.x, v0.x, p); p = fmaf(v0.y, v0.y, p); p = fmaf(v0.z, v0.z, p); p = fmaf(v0.w, v0.w, p);
        p = fmaf(v1.x, v1.x, p); p = fmaf(v1.y, v1.y, p); p = fmaf(v1.z, v1.z, p); p = fmaf(v1.w, v1.w, p);
        p = fmaf(v2.x, v2.x, p); p = fmaf(v2.y, v2.y, p); p = fmaf(v2.z, v2.z, p); p = fmaf(v2.w, v2.w, p);
        p = fmaf(v3.x, v3.x, p); p = fmaf(v3.y, v3.y, p); p = fmaf(v3.z, v3.z, p); p = fmaf(v3.w, v3.w, p);
        p += __shfl_xor(p, 1);
        p += __shfl_xor(p, 2);
        if (q == 0) xx_s[row] = p;

        float hv[16] = {v0.x, v0.y, v0.z, v0.w, v1.x, v1.y, v1.z, v1.w,
                        v2.x, v2.y, v2.z, v2.w, v3.x, v3.y, v3.z, v3.w};
        bf16x8 ph[2], pl[2];
#pragma unroll
        for (int h = 0; h < 2; ++h)
#pragma unroll
            for (int e = 0; e < 8; ++e) {
                float v = hv[h * 8 + e];
                unsigned short hb = f2bf(v);
                float hf = __uint_as_float(((unsigned)hb) << 16);
                ph[h][e] = (short)hb;
                pl[h][e] = (short)f2bf(v - hf);
            }
        const int sw = row & 7;
        char* base = bX + row * 256;
#pragma unroll
        for (int h = 0; h < 2; ++h) {
            int s3 = (2 * q + h) ^ sw;
            *(bf16x8*)(base + (s3 & 7) * 16)        = ph[h];
            *(bf16x8*)(base + (8 | (s3 & 7)) * 16)  = pl[h];
        }
    }
    __syncthreads();

    bf16x8 afh[2][2], afl[2][2];
#pragma unroll
    for (int rt = 0; rt < 2; ++rt)
#pragma unroll
        for (int kt = 0; kt < 2; ++kt) {
            int row = rh * 32 + rt * 16 + (lane & 15);
            int s3 = ((kt * 4 + (lane >> 4)) ^ (row & 7)) & 7;
            afh[rt][kt] = *(const bf16x8*)(bX + row * 256 + s3 * 16);
            afl[rt][kt] = *(const bf16x8*)(bX + row * 256 + (8 | s3) * 16);
        }

    const int cl = ct * 16 + (lane & 15);

    float m1[8], m2[8];
    int   mi[8];
#pragma unroll
    for (int s = 0; s < 8; ++s) { m1[s] = 3.4e38f; m2[s] = 3.4e38f; mi[s] = 0; }

    const char* pc = cbt + (size_t)ct * 4096 + (size_t)lane * 16;

    bf16x8 bh0 = *(const bf16x8*)(pc);
    bf16x8 bh1 = *(const bf16x8*)(pc + 1024);
    bf16x8 bl0 = *(const bf16x8*)(pc + 2048);
    bf16x8 bl1 = *(const bf16x8*)(pc + 3072);

#pragma unroll 1
    for (int c2 = 0; c2 < 32; ++c2) {
        const char* np = pc + 8192;
        bf16x8 nh0 = *(const bf16x8*)(np);
        bf16x8 nh1 = *(const bf16x8*)(np + 1024);
        bf16x8 nl0 = *(const bf16x8*)(np + 2048);
        bf16x8 nl1 = *(const bf16x8*)(np + 3072);

        const int kg = c2 * 32 + cl;
        const float cbnv = cbn_s[kg];

#pragma unroll
        for (int rt = 0; rt < 2; ++rt) {
            f32x4 z = {0.f, 0.f, 0.f, 0.f};
            z = __builtin_amdgcn_mfma_f32_16x16x32_bf16(afh[rt][0], bh0, z, 0, 0, 0);
            z = __builtin_amdgcn_mfma_f32_16x16x32_bf16(afh[rt][1], bh1, z, 0, 0, 0);
            z = __builtin_amdgcn_mfma_f32_16x16x32_bf16(afl[rt][0], bh0, z, 0, 0, 0);
            z = __builtin_amdgcn_mfma_f32_16x16x32_bf16(afl[rt][1], bh1, z, 0, 0, 0);
            z = __builtin_amdgcn_mfma_f32_16x16x32_bf16(afh[rt][0], bl0, z, 0, 0, 0);
            z = __builtin_amdgcn_mfma_f32_16x16x32_bf16(afh[rt][1], bl1, z, 0, 0, 0);
#pragma unroll
            for (int v = 0; v < 4; ++v) {
                const int s = rt * 4 + v;
                float dd = fmaf(-2.f, z[v], cbnv);
                bool lt = dd < m1[s];
                m2[s] = fminf(m2[s], fmaxf(m1[s], dd));
                m1[s] = fminf(m1[s], dd);
                mi[s] = lt ? kg : mi[s];
            }
        }
        pc = np;
        bh0 = nh0; bh1 = nh1; bl0 = nl0; bl1 = nl1;
    }

#pragma unroll
    for (int m = 1; m <= 8; m <<= 1) {
#pragma unroll
        for (int s = 0; s < 8; ++s) {
            float o1 = __shfl_xor(m1[s], m);
            float o2 = __shfl_xor(m2[s], m);
            int   oi = __shfl_xor(mi[s], m);
            float nm2 = fminf(fminf(m2[s], o2), fmaxf(m1[s], o1));
            bool tk = (o1 < m1[s]) || (o1 == m1[s] && oi < mi[s]);
            m1[s] = fminf(m1[s], o1);
            mi[s] = tk ? oi : mi[s];
            m2[s] = nm2;
        }
    }
    __syncthreads();
    if ((lane & 15) == 0) {
        const int gq = lane >> 4;
#pragma unroll
        for (int s = 0; s < 8; ++s) {
            const int row = rh * 32 + (s >> 2) * 16 + gq * 4 + (s & 3);
            R1[row * 2 + ct]  = m1[s];
            R2v[row * 2 + ct] = m2[s];
            RIv[row * 2 + ct] = mi[s];
        }
    }
    __syncthreads();

    bool flag = false;
    int  rr = 0;
    if (t < 128) {
        const int row = t >> 1, q = t & 1;
        float a1 = R1[row * 2 + q];
        float A2 = R2v[row * 2 + q];
        int   ai = RIv[row * 2 + q];
        {
            float o1 = __shfl_xor(a1, 1);
            float o2 = __shfl_xor(A2, 1);
            int   oi = __shfl_xor(ai, 1);
            float nm2 = fminf(fminf(A2, o2), fmaxf(a1, o1));
            bool tk = (o1 < a1) || (o1 == a1 && oi < ai);
            a1 = fminf(a1, o1);
            ai = tk ? oi : ai;
            A2 = nm2;
        }
        if (q == 0) {
            const int r = r0 + row;
            out_idx[r] = (float)ai;
            const float Bv = 1.5e-4f * sqrtf(xx_s[row] * maxcbn) + 2e-3f;
            flag = (A2 - a1 <= 2.f * Bv);
            rr = r;
        }
    }
    unsigned long long mk = __ballot(flag);
    const int wcnt = __popcll(mk);
    if (lane == 0) cntL[w] = wcnt;
    __syncthreads();
    if (t == 0) {
        int c0 = cntL[0], c1 = cntL[1], c2 = cntL[2], c3 = cntL[3];
        int tot = c0 + c1 + c2 + c3;
        int base = 0;
        if (tot) base = atomicAdd((int*)(ws + WSO_COUNT), tot);
        cntL[0] = base;
        cntL[1] = base + c0;
        cntL[2] = base + c0 + c1;
        cntL[3] = base + c0 + c1 + c2;
    }
    __syncthreads();
    if (flag) {
        const int off = __popcll(mk & ((1ull << lane) - 1ull));
        list[cntL[w] + off] = (unsigned short)rr;
    }
}

// ---- kernel 2: refine v3 (R12 verbatim) ----
__global__ void vq_refine(const float* __restrict__ x,
                          const float* __restrict__ cb,
                          const char* __restrict__ ws,
                          const unsigned short* __restrict__ list,
                          float* __restrict__ out_idx) {
    const int N = *(const int*)(ws + WSO_COUNT);
    const float* cbn = (const float*)(ws + WSO_CBN);
    __shared__ float rowx[4][64];
    const int t = threadIdx.x, w = t >> 6, lane = t & 63;

    for (int base = blockIdx.x * 4; base < N; base += (int)gridDim.x * 4) {
        const int ii = base + w;
        const bool valid = ii < N;
        const int r = valid ? (int)list[ii] : (int)list[0];

        __syncthreads();
        const float xv = x[(size_t)r * DIM + lane];
        rowx[w][lane] = xv;
        float p = xv * xv;
#pragma unroll
        for (int m = 1; m < 64; m <<= 1) p += __shfl_xor(p, m);
        const float xx = p;
        __syncthreads();

        float xr[64];
#pragma unroll
        for (int d = 0; d < 64; ++d) xr[d] = rowx[w][d];

        float bd = 3.4e38f;
        int   bk = 0;
        for (int kb = 0; kb < NCODE; kb += 64) {
            float d0 = 0.f, d1 = 0.f, d2 = 0.f, d3 = 0.f;
            const float* cp = cb + kb + lane;
#pragma unroll
            for (int d = 0; d < 64; d += 4) {
                d0 = fmaf(xr[d + 0], cp[(d + 0) * NCODE], d0);
                d1 = fmaf(xr[d + 1], cp[(d + 1) * NCODE], d1);
                d2 = fmaf(xr[d + 2], cp[(d + 2) * NCODE], d2);
                d3 = fmaf(xr[d + 3], cp[(d + 3) * NCODE], d3);
            }
            const float dot = (d0 + d1) + (d2 + d3);
            const float dist = fmaf(-2.f, dot, xx) + cbn[kb + lane];
            const int k = kb + lane;
            if (dist < bd) { bd = dist; bk = k; }
        }
#pragma unroll
        for (int m = 1; m < 64; m <<= 1) {
            float od = __shfl_xor(bd, m);
            int   ok = __shfl_xor(bk, m);
            if (od < bd || (od == bd && ok < bk)) { bd = od; bk = ok; }
        }
        if (lane == 0 && valid) out_idx[r] = (float)bk;
    }
}

// ---- kernel 2b: atomic-free histogram: 32 blocks x 2048 rows -> LDS -> private partial ----
__global__ __launch_bounds__(256) void vq_hist(const float* __restrict__ idx_f,
                                               float* __restrict__ partials) {
    __shared__ int lh[1024];
    const int t = threadIdx.x;
    lh[t] = 0; lh[t + 256] = 0; lh[t + 512] = 0; lh[t + 768] = 0;
    __syncthreads();
    const int base = blockIdx.x * 2048;
#pragma unroll
    for (int i = 0; i < 8; ++i) {
        int k = (int)idx_f[base + i * 256 + t];
        atomicAdd(&lh[k], 1);                 // LDS atomic: ~ns, conflict-rare
    }
    __syncthreads();
    float* P = partials + (size_t)blockIdx.x * 1024;
    P[t]       = (float)lh[t];
    P[t + 256] = (float)lh[t + 256];
    P[t + 512] = (float)lh[t + 512];
    P[t + 768] = (float)lh[t + 768];
}

// ---- kernel 2c: freq = EMA(cf, sum of 32 partials)  (runs BEFORE E1 overwrites partials) ----
__global__ __launch_bounds__(256) void vq_freq(const float* __restrict__ cf,
                                               const float* __restrict__ partials,
                                               float* __restrict__ out_freq) {
    const int k = blockIdx.x * 256 + threadIdx.x;
    float s = 0.f;
#pragma unroll
    for (int b = 0; b < 32; ++b) s += partials[(size_t)b * 1024 + k];   // coalesced
    out_freq[k] = 0.95f * cf[k] + 0.05f * s;
}

// ---- kernel 3a: epilogue E1 — cbT gather; loss slots in ws; NO hist atomic ----
__global__ __launch_bounds__(256) void vq_epi_main(const float* __restrict__ x,
                                                   const float* __restrict__ cbT,
                                                   const float* __restrict__ idx_f,
                                                   float* __restrict__ out_xq,
                                                   char* __restrict__ ws) {
    __shared__ float lred[4];
    const int t = threadIdx.x;
    const int r_lin = blockIdx.x * 32 + (t >> 3);
    const int r = (r_lin < 1024) ? r_lin : r_lin + 1024;   // skip cbT rows
    const int q8 = t & 7;
    const int k = (int)idx_f[r];

    const float4* cp = (const float4*)(cbT + (size_t)k * 64 + q8 * 8);
    const float4* xp = (const float4*)(x + (size_t)r * DIM + q8 * 8);
    float4* op = (float4*)(out_xq + (size_t)r * DIM + q8 * 8);

    float4 c0 = cp[0], c1 = cp[1];
    float4 x0 = xp[0], x1 = xp[1];
    float e0 = c0.x - x0.x, e1 = c0.y - x0.y, e2 = c0.z - x0.z, e3 = c0.w - x0.w;
    float e4 = c1.x - x1.x, e5 = c1.y - x1.y, e6 = c1.z - x1.z, e7 = c1.w - x1.w;
    float4 o0, o1;
    o0.x = x0.x + e0; o0.y = x0.y + e1; o0.z = x0.z + e2; o0.w = x0.w + e3;
    o1.x = x1.x + e4; o1.y = x1.y + e5; o1.z = x1.z + e6; o1.w = x1.w + e7;
    op[0] = o0; op[1] = o1;

    float lsum = 0.f;
    lsum = fmaf(e0, e0, lsum); lsum = fmaf(e1, e1, lsum);
    lsum = fmaf(e2, e2, lsum); lsum = fmaf(e3, e3, lsum);
    lsum = fmaf(e4, e4, lsum); lsum = fmaf(e5, e5, lsum);
    lsum = fmaf(e6, e6, lsum); lsum = fmaf(e7, e7, lsum);

#pragma unroll
    for (int off = 1; off < 64; off <<= 1) lsum += __shfl_xor(lsum, off);
    if ((t & 63) == 0) lred[t >> 6] = lsum;
    __syncthreads();
    if (t == 0)
        atomicAdd((float*)(ws + WSO_SLOTS) + (blockIdx.x & 255),
                  (lred[0] + lred[1]) + (lred[2] + lred[3]));
}

// ---- kernel 3b: epilogue E2 — rows 1024..2047, direct-cb gather; NO hist atomic ----
__global__ __launch_bounds__(256) void vq_epi_tail(const float* __restrict__ x,
                                                   const float* __restrict__ cb,
                                                   const float* __restrict__ idx_f,
                                                   float* __restrict__ out_xq,
                                                   char* __restrict__ ws) {
    __shared__ float lred[4];
    const int t = threadIdx.x;
    const int row = 1024 + blockIdx.x * 64 + (t >> 2), q = t & 3;
    const int k = (int)idx_f[row];
    const float4* xp = (const float4*)(x + (size_t)row * DIM + q * 16);
    float4* op = (float4*)(out_xq + (size_t)row * DIM + q * 16);
    float lsum = 0.f;
#pragma unroll
    for (int j = 0; j < 4; ++j) {
        float4 xv = xp[j];
        const int d0 = q * 16 + 4 * j;
        float q0 = cb[(d0 + 0) * NCODE + k];
        float q1 = cb[(d0 + 1) * NCODE + k];
        float q2 = cb[(d0 + 2) * NCODE + k];
        float q3 = cb[(d0 + 3) * NCODE + k];
        float e0 = q0 - xv.x, e1 = q1 - xv.y, e2 = q2 - xv.z, e3 = q3 - xv.w;
        float4 o;
        o.x = xv.x + e0; o.y = xv.y + e1; o.z = xv.z + e2; o.w = xv.w + e3;
        op[j] = o;
        lsum = fmaf(e0, e0, lsum); lsum = fmaf(e1, e1, lsum);
        lsum = fmaf(e2, e2, lsum); lsum = fmaf(e3, e3, lsum);
    }
#pragma unroll
    for (int off = 1; off < 64; off <<= 1) lsum += __shfl_xor(lsum, off);
    if ((t & 63) == 0) lred[t >> 6] = lsum;
    __syncthreads();
    if (t == 0)
        atomicAdd((float*)(ws + WSO_SLOTS) + blockIdx.x,
                  (lred[0] + lred[1]) + (lred[2] + lred[3]));
}

// ---- kernel 4: loss finalize (freq already written by vq_freq) ----
__global__ __launch_bounds__(256) void vq_loss(const char* __restrict__ ws,
                                               float* __restrict__ out_loss) {
    __shared__ float red[256];
    const int t = threadIdx.x;
    red[t] = ((const float*)(ws + WSO_SLOTS))[t];
    __syncthreads();
    for (int m = 128; m > 0; m >>= 1) {
        if (t < m) red[t] += red[t + m];
        __syncthreads();
    }
    if (t == 0) {
        float m = red[0] / 4194304.0f;
        out_loss[0] = m + m;
    }
}

extern "C" void kernel_launch(void* const* d_in, const int* in_sizes, int n_in,
                              void* d_out, int out_size, void* d_ws, size_t ws_size,
                              hipStream_t stream) {
    const float* x  = (const float*)d_in[0];   // [16,4096,64]
    const float* cb = (const float*)d_in[1];   // [64,1024]
    const float* cf = (const float*)d_in[2];   // [1024]

    float* out      = (float*)d_out;
    float* out_xq   = out;                     // 4,194,304 floats
    float* out_idx  = out + 4194304;           // 65,536
    float* out_loss = out + 4194304 + 65536;   // 1
    float* out_freq = out_loss + 1;            // 1024

    char* ws = (char*)d_ws;                    // 8,256 bytes used

    char*           cbt   = (char*)d_out;                               // 262,144 B
    float*          cbT   = (float*)((char*)d_out + 262144);            // 262,144 B
    unsigned short* list  = (unsigned short*)((char*)d_out + 524288);   // 131,072 B
    float*          parts = (float*)((char*)d_out + 524288);            // 32x4KB partials (reuses list)

    vq_prep    <<<4,    256, 0, stream>>>(cb, ws, cbt, cbT);
    vq_mfma    <<<1024, 256, 0, stream>>>(x, cbt, ws, list, out_idx);
    vq_refine  <<<2048, 256, 0, stream>>>(x, cb, ws, list, out_idx);
    vq_hist    <<<32,   256, 0, stream>>>(out_idx, parts);
    vq_freq    <<<4,    256, 0, stream>>>(cf, parts, out_freq);
    vq_epi_main<<<2016, 256, 0, stream>>>(x, cbT, out_idx, out_xq, ws);
    vq_epi_tail<<<16,   256, 0, stream>>>(x, cb, out_idx, out_xq, ws);
    vq_loss    <<<1,    256, 0, stream>>>(ws, out_loss);
}